// Round 1
// baseline (262.266 us; speedup 1.0000x reference)
//
#include <hip/hip_runtime.h>

// SSIM loss, fused single kernel.
// imgs: (16,3,512,512) fp32. Output: scalar fp32 mean loss.
// Separable 11-tap Gaussian (sigma=1.5), zero padding (matches jax conv pad).

#define BATCH 16
#define CHAN  3
#define H_    512
#define W_    512
#define TW    64     // tile width (output)
#define TH    16     // tile height (output)
#define HALO  5
#define SROWS (TH + 2*HALO)   // 26 staged input rows
#define SCOLS (TW + 2*HALO)   // 74 staged input cols (used)
#define SW    76              // LDS stride for input stage (16B aligned rows)
#define NPIX  ((long)BATCH*CHAN*H_*W_)

__device__ __forceinline__ float ssim_loss_px(float mu1, float mu2,
                                              float x11, float x22, float x12) {
    const float c1 = 1.0e-4f;  // (0.01*1.0)^2
    const float c2 = 9.0e-4f;  // (0.03*1.0)^2
    float mu1s = mu1 * mu1;
    float mu2s = mu2 * mu2;
    float m12  = mu1 * mu2;
    float s1v  = x11 - mu1s;
    float s2v  = x22 - mu2s;
    float s12  = x12 - m12;
    float num  = (2.0f * m12 + c1) * (2.0f * s12 + c2);
    float den  = (mu1s + mu2s + c1) * (s1v + s2v + c2);
    float ssim = num / den;
    float l = 1.0f - ssim;
    return fminf(fmaxf(l, 0.0f), 1.0f);
}

__global__ __launch_bounds__(256) void ssim_kernel(const float* __restrict__ img1,
                                                   const float* __restrict__ img2,
                                                   float* __restrict__ out) {
    __shared__ __align__(16) float s1[SROWS * SW];
    __shared__ __align__(16) float s2[SROWS * SW];
    __shared__ __align__(16) float hb[5][SROWS * TW];
    __shared__ float wsum4[4];

    const int tid = threadIdx.x;

    // Gaussian weights (normalized), computed per-thread (negligible cost).
    float w[11];
    {
        float s = 0.0f;
#pragma unroll
        for (int i = 0; i < 11; ++i) {
            float x = (float)(i - 5);
            w[i] = expf(-(x * x) / 4.5f);
            s += w[i];
        }
        float inv = 1.0f / s;
#pragma unroll
        for (int i = 0; i < 11; ++i) w[i] *= inv;
    }

    // ---------------- Stage A: global -> LDS (with halo, zero pad) ----------
    const int plane = blockIdx.z;                  // b*3 + c
    const long base = (long)plane * (H_ * W_);
    const int gx0 = blockIdx.x * TW - HALO;
    const int gy0 = blockIdx.y * TH - HALO;

    for (int i = tid; i < SROWS * SCOLS; i += 256) {
        int r = i / SCOLS;
        int c = i - r * SCOLS;
        int gy = gy0 + r;
        int gx = gx0 + c;
        bool ok = (gy >= 0) && (gy < H_) && (gx >= 0) && (gx < W_);
        long off = ok ? (base + (long)gy * W_ + gx) : 0;
        float v1 = ok ? img1[off] : 0.0f;
        float v2 = ok ? img2[off] : 0.0f;
        s1[r * SW + c] = v1;
        s2[r * SW + c] = v2;
    }
    __syncthreads();

    // ---------------- Stage B: horizontal 11-tap, 5 quantities fused --------
    // 26 rows x 16 col-quads = 416 tasks; each task produces 4 consecutive
    // h-outputs from 16 staged floats (aligned float4 LDS reads).
    for (int t = tid; t < SROWS * (TW / 4); t += 256) {
        int r  = t >> 4;
        int c0 = (t & 15) << 2;
        const float* p1 = &s1[r * SW + c0];
        const float* p2 = &s2[r * SW + c0];
        float a[16], b[16];
#pragma unroll
        for (int j = 0; j < 4; ++j) {
            float4 va = *(const float4*)&p1[4 * j];
            float4 vb = *(const float4*)&p2[4 * j];
            a[4*j+0] = va.x; a[4*j+1] = va.y; a[4*j+2] = va.z; a[4*j+3] = va.w;
            b[4*j+0] = vb.x; b[4*j+1] = vb.y; b[4*j+2] = vb.z; b[4*j+3] = vb.w;
        }
        float m1[4]  = {0, 0, 0, 0};
        float m2[4]  = {0, 0, 0, 0};
        float m11[4] = {0, 0, 0, 0};
        float m22[4] = {0, 0, 0, 0};
        float m12[4] = {0, 0, 0, 0};
#pragma unroll
        for (int k = 0; k < 11; ++k) {
            float wk = w[k];
#pragma unroll
            for (int j = 0; j < 4; ++j) {
                float aa = a[k + j];
                float bb = b[k + j];
                float t1 = wk * aa;
                float t2 = wk * bb;
                m1[j]  += t1;
                m2[j]  += t2;
                m11[j] = fmaf(t1, aa, m11[j]);
                m22[j] = fmaf(t2, bb, m22[j]);
                m12[j] = fmaf(t1, bb, m12[j]);
            }
        }
        int ho = r * TW + c0;
        *(float4*)&hb[0][ho] = make_float4(m1[0],  m1[1],  m1[2],  m1[3]);
        *(float4*)&hb[1][ho] = make_float4(m2[0],  m2[1],  m2[2],  m2[3]);
        *(float4*)&hb[2][ho] = make_float4(m11[0], m11[1], m11[2], m11[3]);
        *(float4*)&hb[3][ho] = make_float4(m22[0], m22[1], m22[2], m22[3]);
        *(float4*)&hb[4][ho] = make_float4(m12[0], m12[1], m12[2], m12[3]);
    }
    __syncthreads();

    // ---------------- Stage C: vertical 11-tap, 2x2 px per thread ----------
    const int tx = tid & 31;   // col-pair index
    const int ty = tid >> 5;   // row-pair index (0..7)
    const int c0 = tx << 1;
    const int y0 = ty << 1;

    float V00[5], V01[5], V10[5], V11[5];  // [q] for px (y0,c0),(y0,c0+1),(y0+1,c0),(y0+1,c0+1)
#pragma unroll
    for (int q = 0; q < 5; ++q) {
        float r0[12], r1[12];
#pragma unroll
        for (int k = 0; k < 12; ++k) {
            float2 v = *(const float2*)&hb[q][(y0 + k) * TW + c0];
            r0[k] = v.x;
            r1[k] = v.y;
        }
        float a0 = 0, a1 = 0, b0 = 0, b1 = 0;
#pragma unroll
        for (int k = 0; k < 11; ++k) {
            a0 = fmaf(w[k], r0[k],     a0);
            a1 = fmaf(w[k], r1[k],     a1);
            b0 = fmaf(w[k], r0[k + 1], b0);
            b1 = fmaf(w[k], r1[k + 1], b1);
        }
        V00[q] = a0; V01[q] = a1; V10[q] = b0; V11[q] = b1;
    }

    float local = ssim_loss_px(V00[0], V00[1], V00[2], V00[3], V00[4])
                + ssim_loss_px(V01[0], V01[1], V01[2], V01[3], V01[4])
                + ssim_loss_px(V10[0], V10[1], V10[2], V10[3], V10[4])
                + ssim_loss_px(V11[0], V11[1], V11[2], V11[3], V11[4]);

    // ---------------- Reduction --------------------------------------------
#pragma unroll
    for (int off = 32; off > 0; off >>= 1) local += __shfl_down(local, off);
    if ((tid & 63) == 0) wsum4[tid >> 6] = local;
    __syncthreads();
    if (tid == 0) {
        float bs = wsum4[0] + wsum4[1] + wsum4[2] + wsum4[3];
        atomicAdd(out, bs * (0.5f / (float)NPIX));
    }
}

extern "C" void kernel_launch(void* const* d_in, const int* in_sizes, int n_in,
                              void* d_out, int out_size, void* d_ws, size_t ws_size,
                              hipStream_t stream) {
    const float* img1 = (const float*)d_in[0];
    const float* img2 = (const float*)d_in[1];
    float* out = (float*)d_out;

    // Harness re-poisons d_out to 0xAA before every timed launch; zero it.
    hipMemsetAsync(out, 0, sizeof(float), stream);

    dim3 grid(W_ / TW, H_ / TH, BATCH * CHAN);  // 8 x 32 x 48
    ssim_kernel<<<grid, 256, 0, stream>>>(img1, img2, out);
}